// Round 1
// baseline (195.618 us; speedup 1.0000x reference)
//
#include <hip/hip_runtime.h>
#include <hip/hip_bf16.h>
#include <stdint.h>

#define N_NODES 50000
#define N_EDGES 800000
#define IN_CH   128
#define NEG_SLOPE 0.2f

#define PROJ_BLOCKS 782          // ceil(3125 waves / 4); waves cover 16 rows each
#define E_PER 8                  // edges per fill thread (ILP on the atomic chain)
#define FILL_BLOCKS 391          // ceil(800000 / (256*8))

typedef short short8 __attribute__((ext_vector_type(8)));
typedef float f32x4  __attribute__((ext_vector_type(4)));
typedef float f32x2  __attribute__((ext_vector_type(2)));

static __device__ __forceinline__ float bf_lo(uint32_t p) { return __uint_as_float(p << 16); }
static __device__ __forceinline__ float bf_hi(uint32_t p) { return __uint_as_float(p & 0xffff0000u); }
static __device__ __forceinline__ uint16_t f_to_bf(float f) {
    uint32_t u = __float_as_uint(f);
    u += 0x7fffu + ((u >> 16) & 1u);   // round-to-nearest-even
    return (uint16_t)(u >> 16);
}
static __device__ __forceinline__ float lrelu(float x) { return fmaxf(x, NEG_SLOPE * x); }

// 16-lane sum-broadcast, pure VALU via DPP butterfly (xor1,xor2,half/row
// mirror): every lane ends with the full 16-lane sum.  No LDS traffic.
static __device__ __forceinline__ float sum16(float x) {
    x += __uint_as_float(__builtin_amdgcn_update_dpp(0, __float_as_uint(x), 0xB1,  0xf, 0xf, true)); // quad_perm[1,0,3,2]
    x += __uint_as_float(__builtin_amdgcn_update_dpp(0, __float_as_uint(x), 0x4E,  0xf, 0xf, true)); // quad_perm[2,3,0,1]
    x += __uint_as_float(__builtin_amdgcn_update_dpp(0, __float_as_uint(x), 0x141, 0xf, 0xf, true)); // row_half_mirror
    x += __uint_as_float(__builtin_amdgcn_update_dpp(0, __float_as_uint(x), 0x140, 0xf, 0xf, true)); // row_mirror
    return x;
}

// ---------------------------------------------------------------------------
// prep: (a) swizzle Wl/Wr (f32) -> bf16 in MFMA B-fragment order;
//       (b) zero the cnt array (grid-stride).  One dispatch.
// ---------------------------------------------------------------------------
__global__ __launch_bounds__(256) void prep_kernel(
    const float* __restrict__ Wl, const float* __restrict__ Wr,
    __hip_bfloat16* __restrict__ wswz, int* __restrict__ cnt)
{
    int t = blockIdx.x * 256 + threadIdx.x;   // 64 blocks x 256 = 16384
    if (t < 4096) {
        int ct = t >> 8, rem = t & 255;
        int ch = rem >> 6, lane = rem & 63;
        int m = lane & 15, quad = lane >> 4;
        const float* W = (ct < 8) ? Wl : Wr;
        int o = ((ct & 7) << 4) + m;
        const float* src = W + (size_t)o * IN_CH + ch * 32 + quad * 8;
        short8 f;
#pragma unroll
        for (int j = 0; j < 8; ++j) f[j] = (short)f_to_bf(src[j]);
        *(short8*)((short*)wswz + (size_t)t * 8) = f;
    }
    for (int i = t; i < N_NODES; i += 64 * 256) cnt[i] = 0;
}

// ---------------------------------------------------------------------------
// mid: fused proj + fill (independent work, disjoint block ranges).
//   blocks [0, PROJ_BLOCKS):            xl = x@Wl^T+bl -> f32 (d_out),
//                                       xr = x@Wr^T+br -> bf16 (ws)
//   blocks [PROJ_BLOCKS, +FILL_BLOCKS): bucket-CSR build, 8 edges/thread
//                                       (independent atomics pipeline).
//   R1: csr scatter is NON-TEMPORAL.  Each node's csr slab is exactly one
//   128B line written ~16x by random blocks across 8 non-coherent L2s ->
//   partial-line bounce write-backs (WRITE_SIZE 83MB vs ~40MB ideal).
//   nt stores bypass L2 residency -> no bounce.
// ---------------------------------------------------------------------------
__global__ __launch_bounds__(256) void mid_kernel(
    const float* __restrict__ x,
    const __hip_bfloat16* __restrict__ wswz,
    const float* __restrict__ bl, const float* __restrict__ br,
    float* __restrict__ xl, __hip_bfloat16* __restrict__ xr,
    const int* __restrict__ ei, int cap,
    int* __restrict__ cnt, uint16_t* __restrict__ csr)
{
    if (blockIdx.x < PROJ_BLOCKS) {
        // ----- projection -----
        int wave = blockIdx.x * 4 + (threadIdx.x >> 6);
        int rowbase = wave * 16;
        if (rowbase >= N_NODES) return;
        int lane = threadIdx.x & 63;
        int m = lane & 15;        // A row / B col within tile
        int quad = lane >> 4;     // k-group selector

        short8 afrag[4];
        const float* xrow = x + (size_t)(rowbase + m) * IN_CH;
#pragma unroll
        for (int ch = 0; ch < 4; ++ch) {
            f32x4 p0 = *(const f32x4*)(xrow + ch * 32 + quad * 8);
            f32x4 p1 = *(const f32x4*)(xrow + ch * 32 + quad * 8 + 4);
            short8 f;
#pragma unroll
            for (int j = 0; j < 4; ++j) { f[j] = (short)f_to_bf(p0[j]); f[j + 4] = (short)f_to_bf(p1[j]); }
            afrag[ch] = f;
        }

        const short* wz = (const short*)wswz;
#pragma unroll
        for (int ct = 0; ct < 16; ++ct) {
            const float* bv = (ct < 8) ? bl : br;
            int o = ((ct & 7) << 4) + m;   // output column (0..127)
            f32x4 acc = {0.f, 0.f, 0.f, 0.f};
#pragma unroll
            for (int ch = 0; ch < 4; ++ch) {
                short8 bfrag = *(const short8*)(wz + ((size_t)(ct * 4 + ch) * 64 + lane) * 8);
                acc = __builtin_amdgcn_mfma_f32_16x16x32_bf16(afrag[ch], bfrag, acc, 0, 0, 0);
            }
            float bias_v = bv[o];
            // D layout: row = quad*4 + r, col = m   [m89-verified]
            // stores coalesce: per (ct,r) 4 rows x 64B full lines
            if (ct < 8) {
#pragma unroll
                for (int r = 0; r < 4; ++r)
                    xl[(size_t)(rowbase + quad * 4 + r) * IN_CH + o] = acc[r] + bias_v;
            } else {
#pragma unroll
                for (int r = 0; r < 4; ++r)
                    xr[(size_t)(rowbase + quad * 4 + r) * IN_CH + o] = __float2bfloat16(acc[r] + bias_v);
            }
        }
    } else {
        // ----- CSR fill: 8 edges per thread -----
        const uint32_t* eiw = (const uint32_t*)ei;
        bool z = (eiw[2 * (threadIdx.x & 63) + 1] == 0u);
        bool is64 = __popcll(__ballot(z)) >= 32;

        int tid = (blockIdx.x - PROJ_BLOCKS) * 256 + threadIdx.x;
        int e0 = tid * E_PER;
        if (e0 >= N_EDGES) return;   // 800000 % 8 == 0: no partial batches

        int src[E_PER], tgt[E_PER];
        if (is64) {
            // 8 edges = 16 dwords (low/high interleaved), 64B-aligned
            const int4* ps = (const int4*)(eiw + 2 * (size_t)e0);
            const int4* pt = (const int4*)(eiw + 2 * ((size_t)N_EDGES + e0));
#pragma unroll
            for (int k = 0; k < 4; ++k) {
                int4 s = ps[k], t = pt[k];
                src[2 * k] = s.x; src[2 * k + 1] = s.z;
                tgt[2 * k] = t.x; tgt[2 * k + 1] = t.z;
            }
        } else {
            const int4* ps = (const int4*)(ei + e0);
            const int4* pt = (const int4*)(ei + N_EDGES + e0);
#pragma unroll
            for (int k = 0; k < 2; ++k) {
                int4 s = ps[k], t = pt[k];
                src[4 * k] = s.x; src[4 * k + 1] = s.y; src[4 * k + 2] = s.z; src[4 * k + 3] = s.w;
                tgt[4 * k] = t.x; tgt[4 * k + 1] = t.y; tgt[4 * k + 2] = t.z; tgt[4 * k + 3] = t.w;
            }
        }

        int pos[E_PER];
#pragma unroll
        for (int k = 0; k < E_PER; ++k) {
            bool ok = (unsigned)src[k] < N_NODES && (unsigned)tgt[k] < N_NODES;
            pos[k] = ok ? atomicAdd(&cnt[tgt[k]], 1) : cap;   // cap => dropped below
        }
#pragma unroll
        for (int k = 0; k < E_PER; ++k)
            if (pos[k] < cap)
                __builtin_nontemporal_store((uint16_t)src[k],
                                            &csr[(size_t)tgt[k] * cap + pos[k]]);   // R1: nt
    }
}

// ---------------------------------------------------------------------------
// Fused attention + aggregation: one wave per target node.
// Unguarded softmax (|t| <~ 8 << 88: exp never overflows; identical math).
// Neighbor ids preloaded to idxreg, distributed via v_readlane (SGPR base ->
// zero per-lane address VALU on the gather).  Score reduce = DPP sum16.
// R1: software pipeline depth 2 — 2 edges/iter with FOUR row loads in
// flight (pairs P0=(i,i+1), P1=(i+2,i+3); issue P2=(i+4,i+5) each iter).
// Clamped indices are always valid neighbor ids -> loads always in-bounds;
// duplicate-clamped tail loads hit hot lines.
// q read f32 from out (own row), result overwrites it (same wave, RAW-safe).
// ---------------------------------------------------------------------------
__global__ __launch_bounds__(256) void agg_kernel(
    const __hip_bfloat16* __restrict__ xr,
    const int* __restrict__ cnt, const uint16_t* __restrict__ csr, int cap,
    const float* __restrict__ att, const float* __restrict__ bias,
    float* out /* holds xl on entry */)
{
    int n = blockIdx.x * 4 + (threadIdx.x >> 6);
    if (n >= N_NODES) return;
    int lane = threadIdx.x & 63;

    const uint32_t* xrw = (const uint32_t*)xr;   // 64 dwords per node row

    f32x2 qv = *(const f32x2*)(out + (size_t)n * IN_CH + 2 * lane);
    f32x2 av = *(const f32x2*)(att + 2 * lane);
    f32x2 bv = *(const f32x2*)(bias + 2 * lane);

    int deg = min(cnt[n], cap);
    const uint16_t* lst = csr + (size_t)n * cap;
    int idxreg = (int)lst[min(lane, cap - 1)];   // lanes >= deg hold garbage, never selected

    // self-loop
    uint32_t u = xrw[(size_t)n * 64 + lane];
    float v0 = bf_lo(u), v1 = bf_hi(u);
    float t = sum16(lrelu(qv[0] + v0) * av[0] + lrelu(qv[1] + v1) * av[1]);
    float w = __expf(t);
    float lsum = w;
    float acc0 = w * v0, acc1 = w * v1;

    if (deg > 0) {
        int dm1 = deg - 1;
        int s0a = __builtin_amdgcn_readlane(idxreg, 0);
        int s0b = __builtin_amdgcn_readlane(idxreg, min(1, dm1));
        int s1a = __builtin_amdgcn_readlane(idxreg, min(2, dm1));
        int s1b = __builtin_amdgcn_readlane(idxreg, min(3, dm1));
        uint32_t uA0 = xrw[(size_t)s0a * 64 + lane];
        uint32_t uB0 = xrw[(size_t)s0b * 64 + lane];
        uint32_t uA1 = xrw[(size_t)s1a * 64 + lane];
        uint32_t uB1 = xrw[(size_t)s1b * 64 + lane];
        int i = 0;
        while (i + 1 < deg) {
            int s2a = __builtin_amdgcn_readlane(idxreg, min(i + 4, dm1));
            int s2b = __builtin_amdgcn_readlane(idxreg, min(i + 5, dm1));
            uint32_t uA2 = xrw[(size_t)s2a * 64 + lane];
            uint32_t uB2 = xrw[(size_t)s2b * 64 + lane];

            float a0 = bf_lo(uA0), a1 = bf_hi(uA0);
            float b0 = bf_lo(uB0), b1 = bf_hi(uB0);
            float tA = sum16(lrelu(qv[0] + a0) * av[0] + lrelu(qv[1] + a1) * av[1]);
            float tB = sum16(lrelu(qv[0] + b0) * av[0] + lrelu(qv[1] + b1) * av[1]);
            float wA = __expf(tA), wB = __expf(tB);
            lsum += wA + wB;
            acc0 += wA * a0 + wB * b0;
            acc1 += wA * a1 + wB * b1;

            uA0 = uA1; uB0 = uB1;
            uA1 = uA2; uB1 = uB2;
            i += 2;
        }
        if (i < deg) {   // odd tail: uA0 holds edge i (pipeline invariant)
            float a0 = bf_lo(uA0), a1 = bf_hi(uA0);
            float tA = sum16(lrelu(qv[0] + a0) * av[0] + lrelu(qv[1] + a1) * av[1]);
            float wA = __expf(tA);
            lsum += wA;
            acc0 += wA * a0;
            acc1 += wA * a1;
        }
    }

    float inv = 1.f / lsum;
    f32x2 ov;
    ov[0] = acc0 * inv + bv[0];
    ov[1] = acc1 * inv + bv[1];
    *(f32x2*)(out + (size_t)n * IN_CH + 2 * lane) = ov;
}

extern "C" void kernel_launch(void* const* d_in, const int* in_sizes, int n_in,
                              void* d_out, int out_size, void* d_ws, size_t ws_size,
                              hipStream_t stream) {
    const float* x    = (const float*)d_in[0];
    const int*   ei   = (const int*)d_in[1];
    const float* Wl   = (const float*)d_in[2];
    const float* bl   = (const float*)d_in[3];
    const float* Wr   = (const float*)d_in[4];
    const float* br   = (const float*)d_in[5];
    const float* att  = (const float*)d_in[6];
    const float* bias = (const float*)d_in[7];
    float* out = (float*)d_out;

    // workspace layout (bytes):
    //   xr   : [0, 12.8M)                 bf16 [N, 128]
    //   wswz : [12.8M, 12.8M+65536)       bf16 [4096*8]  (swizzled Wl|Wr)
    //   cnt  : [12865536, 13065536)       int  [N]
    //   csr  : [13065536, ...)            u16  [N, cap]
    // xl lives in d_out as f32 (each node's wave reads its own row first).
    const size_t CSR_BASE = 13065536;
    char* ws = (char*)d_ws;
    __hip_bfloat16* xr   = (__hip_bfloat16*)(ws);
    __hip_bfloat16* wswz = (__hip_bfloat16*)(ws + 12800000);
    int*      cnt = (int*)(ws + 12865536);
    uint16_t* csr = (uint16_t*)(ws + CSR_BASE);

    long long avail = (ws_size > CSR_BASE) ? (long long)(ws_size - CSR_BASE) : 0;
    int cap = (int)(avail / ((long long)N_NODES * 2));
    if (cap > 64) cap = 64;
    if (cap < 1)  cap = 1;

    prep_kernel<<<64, 256, 0, stream>>>(Wl, Wr, wswz, cnt);
    mid_kernel<<<PROJ_BLOCKS + FILL_BLOCKS, 256, 0, stream>>>(
        x, wswz, bl, br, out, xr, ei, cap, cnt, csr);
    agg_kernel<<<N_NODES / 4, 256, 0, stream>>>(xr, cnt, csr, cap, att, bias, out);
}

// Round 2
// 180.944 us; speedup vs baseline: 1.0811x; 1.0811x over previous
//
#include <hip/hip_runtime.h>
#include <hip/hip_bf16.h>
#include <stdint.h>

#define N_NODES 50000
#define N_EDGES 800000
#define IN_CH   128
#define NEG_SLOPE 0.2f

#define PROJ_BLOCKS 782          // ceil(3125 waves / 4); waves cover 16 rows each
#define E_PER 8                  // edges per fill thread (ILP on the atomic chain)
#define FILL_BLOCKS 391          // ceil(800000 / (256*8))

typedef short short8 __attribute__((ext_vector_type(8)));
typedef float f32x4  __attribute__((ext_vector_type(4)));
typedef float f32x2  __attribute__((ext_vector_type(2)));
typedef int   i32x4  __attribute__((ext_vector_type(4)));

static __device__ __forceinline__ float bf_lo(uint32_t p) { return __uint_as_float(p << 16); }
static __device__ __forceinline__ float bf_hi(uint32_t p) { return __uint_as_float(p & 0xffff0000u); }
static __device__ __forceinline__ uint16_t f_to_bf(float f) {
    uint32_t u = __float_as_uint(f);
    u += 0x7fffu + ((u >> 16) & 1u);   // round-to-nearest-even
    return (uint16_t)(u >> 16);
}
static __device__ __forceinline__ float lrelu(float x) { return fmaxf(x, NEG_SLOPE * x); }

// 16-lane sum-broadcast, pure VALU via DPP butterfly (xor1,xor2,half/row
// mirror): every lane ends with the full 16-lane sum.  No LDS traffic.
static __device__ __forceinline__ float sum16(float x) {
    x += __uint_as_float(__builtin_amdgcn_update_dpp(0, __float_as_uint(x), 0xB1,  0xf, 0xf, true)); // quad_perm[1,0,3,2]
    x += __uint_as_float(__builtin_amdgcn_update_dpp(0, __float_as_uint(x), 0x4E,  0xf, 0xf, true)); // quad_perm[2,3,0,1]
    x += __uint_as_float(__builtin_amdgcn_update_dpp(0, __float_as_uint(x), 0x141, 0xf, 0xf, true)); // row_half_mirror
    x += __uint_as_float(__builtin_amdgcn_update_dpp(0, __float_as_uint(x), 0x140, 0xf, 0xf, true)); // row_mirror
    return x;
}

// ---------------------------------------------------------------------------
// prep: (a) swizzle Wl/Wr (f32) -> bf16 in MFMA B-fragment order;
//       (b) zero the counter/slab region (coalesced int4 grid-stride).
// ---------------------------------------------------------------------------
__global__ __launch_bounds__(256) void prep_kernel(
    const float* __restrict__ Wl, const float* __restrict__ Wr,
    __hip_bfloat16* __restrict__ wswz, i32x4* __restrict__ zbase, int zchunks)
{
    int t = blockIdx.x * 256 + threadIdx.x;   // 64 blocks x 256 = 16384
    if (t < 4096) {
        int ct = t >> 8, rem = t & 255;
        int ch = rem >> 6, lane = rem & 63;
        int m = lane & 15, quad = lane >> 4;
        const float* W = (ct < 8) ? Wl : Wr;
        int o = ((ct & 7) << 4) + m;
        const float* src = W + (size_t)o * IN_CH + ch * 32 + quad * 8;
        short8 f;
#pragma unroll
        for (int j = 0; j < 8; ++j) f[j] = (short)f_to_bf(src[j]);
        *(short8*)((short*)wswz + (size_t)t * 8) = f;
    }
    i32x4 z = {0, 0, 0, 0};
    for (int i = t; i < zchunks; i += 64 * 256) zbase[i] = z;
}

// ---------------------------------------------------------------------------
// mid: fused proj + fill (independent work, disjoint block ranges).
//   blocks [0, PROJ_BLOCKS):            xl = x@Wl^T+bl -> f32 (d_out),
//                                       xr = x@Wr^T+br -> bf16 (ws)
//   blocks [PROJ_BLOCKS, +FILL_BLOCKS): bucket-CSR build, 8 edges/thread.
//
//   R2: one node = one 128B SLAB  [u32 cnt][62 x u16 nbr].  R1 falsified the
//   nt-store theory but proved fill is mid's critical path; the serializer is
//   cross-XCD atomic line-bounce: int cnt[50000] packs 32 counters/line ->
//   ~512 exclusive-acquisitions per line (~51us, matches 58us measured).
//   Slab layout: ~16 atomics/line, and the pos-store hits the line the atomic
//   just acquired -> absorbed locally (kills the 38MB write excess too).
//   Generic addressing (cstride/estride) keeps a legacy split-array fallback.
// ---------------------------------------------------------------------------
__global__ __launch_bounds__(256) void mid_kernel(
    const float* __restrict__ x,
    const __hip_bfloat16* __restrict__ wswz,
    const float* __restrict__ bl, const float* __restrict__ br,
    float* __restrict__ xl, __hip_bfloat16* __restrict__ xr,
    const int* __restrict__ ei, int cap,
    char* __restrict__ cbase, int cstride,
    char* __restrict__ ebase, int estride)
{
    if (blockIdx.x < PROJ_BLOCKS) {
        // ----- projection -----
        int wave = blockIdx.x * 4 + (threadIdx.x >> 6);
        int rowbase = wave * 16;
        if (rowbase >= N_NODES) return;
        int lane = threadIdx.x & 63;
        int m = lane & 15;        // A row / B col within tile
        int quad = lane >> 4;     // k-group selector

        short8 afrag[4];
        const float* xrow = x + (size_t)(rowbase + m) * IN_CH;
#pragma unroll
        for (int ch = 0; ch < 4; ++ch) {
            f32x4 p0 = *(const f32x4*)(xrow + ch * 32 + quad * 8);
            f32x4 p1 = *(const f32x4*)(xrow + ch * 32 + quad * 8 + 4);
            short8 f;
#pragma unroll
            for (int j = 0; j < 4; ++j) { f[j] = (short)f_to_bf(p0[j]); f[j + 4] = (short)f_to_bf(p1[j]); }
            afrag[ch] = f;
        }

        const short* wz = (const short*)wswz;
#pragma unroll
        for (int ct = 0; ct < 16; ++ct) {
            const float* bv = (ct < 8) ? bl : br;
            int o = ((ct & 7) << 4) + m;   // output column (0..127)
            f32x4 acc = {0.f, 0.f, 0.f, 0.f};
#pragma unroll
            for (int ch = 0; ch < 4; ++ch) {
                short8 bfrag = *(const short8*)(wz + ((size_t)(ct * 4 + ch) * 64 + lane) * 8);
                acc = __builtin_amdgcn_mfma_f32_16x16x32_bf16(afrag[ch], bfrag, acc, 0, 0, 0);
            }
            float bias_v = bv[o];
            // D layout: row = quad*4 + r, col = m   [m89-verified]
            // stores coalesce: per (ct,r) 4 rows x 64B full lines
            if (ct < 8) {
#pragma unroll
                for (int r = 0; r < 4; ++r)
                    xl[(size_t)(rowbase + quad * 4 + r) * IN_CH + o] = acc[r] + bias_v;
            } else {
#pragma unroll
                for (int r = 0; r < 4; ++r)
                    xr[(size_t)(rowbase + quad * 4 + r) * IN_CH + o] = __float2bfloat16(acc[r] + bias_v);
            }
        }
    } else {
        // ----- CSR fill: 8 edges per thread -----
        const uint32_t* eiw = (const uint32_t*)ei;
        bool z = (eiw[2 * (threadIdx.x & 63) + 1] == 0u);
        bool is64 = __popcll(__ballot(z)) >= 32;

        int tid = (blockIdx.x - PROJ_BLOCKS) * 256 + threadIdx.x;
        int e0 = tid * E_PER;
        if (e0 >= N_EDGES) return;   // 800000 % 8 == 0: no partial batches

        int src[E_PER], tgt[E_PER];
        if (is64) {
            // 8 edges = 16 dwords (low/high interleaved), 64B-aligned
            const int4* ps = (const int4*)(eiw + 2 * (size_t)e0);
            const int4* pt = (const int4*)(eiw + 2 * ((size_t)N_EDGES + e0));
#pragma unroll
            for (int k = 0; k < 4; ++k) {
                int4 s = ps[k], t = pt[k];
                src[2 * k] = s.x; src[2 * k + 1] = s.z;
                tgt[2 * k] = t.x; tgt[2 * k + 1] = t.z;
            }
        } else {
            const int4* ps = (const int4*)(ei + e0);
            const int4* pt = (const int4*)(ei + N_EDGES + e0);
#pragma unroll
            for (int k = 0; k < 2; ++k) {
                int4 s = ps[k], t = pt[k];
                src[4 * k] = s.x; src[4 * k + 1] = s.y; src[4 * k + 2] = s.z; src[4 * k + 3] = s.w;
                tgt[4 * k] = t.x; tgt[4 * k + 1] = t.y; tgt[4 * k + 2] = t.z; tgt[4 * k + 3] = t.w;
            }
        }

        int pos[E_PER];
#pragma unroll
        for (int k = 0; k < E_PER; ++k) {
            bool ok = (unsigned)src[k] < N_NODES && (unsigned)tgt[k] < N_NODES;
            pos[k] = ok ? atomicAdd((int*)(cbase + (size_t)tgt[k] * cstride), 1)
                        : cap;   // cap => dropped below
        }
#pragma unroll
        for (int k = 0; k < E_PER; ++k)
            if (pos[k] < cap)
                *(uint16_t*)(ebase + (size_t)tgt[k] * estride + 2 * pos[k]) = (uint16_t)src[k];
    }
}

// ---------------------------------------------------------------------------
// Fused attention + aggregation: one wave per target node.
// Unguarded softmax (|t| <~ 8 << 88: exp never overflows; identical math).
// Neighbor ids preloaded to idxreg, distributed via v_readlane (SGPR base ->
// zero per-lane address VALU on the gather).  Score reduce = DPP sum16.
// Software pipeline depth 2 — 2 edges/iter with FOUR row loads in flight
// (kept from R1: ~-7us).  Slab layout: cnt + neighbor list on ONE 128B line.
// q read f32 from out (own row), result overwrites it (same wave, RAW-safe).
// ---------------------------------------------------------------------------
__global__ __launch_bounds__(256) void agg_kernel(
    const __hip_bfloat16* __restrict__ xr,
    const char* __restrict__ cbase, int cstride,
    const char* __restrict__ ebase, int estride, int cap,
    const float* __restrict__ att, const float* __restrict__ bias,
    float* out /* holds xl on entry */)
{
    int n = blockIdx.x * 4 + (threadIdx.x >> 6);
    if (n >= N_NODES) return;
    int lane = threadIdx.x & 63;

    const uint32_t* xrw = (const uint32_t*)xr;   // 64 dwords per node row

    f32x2 qv = *(const f32x2*)(out + (size_t)n * IN_CH + 2 * lane);
    f32x2 av = *(const f32x2*)(att + 2 * lane);
    f32x2 bv = *(const f32x2*)(bias + 2 * lane);

    int deg = min(*(const int*)(cbase + (size_t)n * cstride), cap);
    const uint16_t* lst = (const uint16_t*)(ebase + (size_t)n * estride);
    int idxreg = (int)lst[min(lane, cap - 1)];   // lanes >= deg hold garbage, never selected

    // self-loop
    uint32_t u = xrw[(size_t)n * 64 + lane];
    float v0 = bf_lo(u), v1 = bf_hi(u);
    float t = sum16(lrelu(qv[0] + v0) * av[0] + lrelu(qv[1] + v1) * av[1]);
    float w = __expf(t);
    float lsum = w;
    float acc0 = w * v0, acc1 = w * v1;

    if (deg > 0) {
        int dm1 = deg - 1;
        int s0a = __builtin_amdgcn_readlane(idxreg, 0);
        int s0b = __builtin_amdgcn_readlane(idxreg, min(1, dm1));
        int s1a = __builtin_amdgcn_readlane(idxreg, min(2, dm1));
        int s1b = __builtin_amdgcn_readlane(idxreg, min(3, dm1));
        uint32_t uA0 = xrw[(size_t)s0a * 64 + lane];
        uint32_t uB0 = xrw[(size_t)s0b * 64 + lane];
        uint32_t uA1 = xrw[(size_t)s1a * 64 + lane];
        uint32_t uB1 = xrw[(size_t)s1b * 64 + lane];
        int i = 0;
        while (i + 1 < deg) {
            int s2a = __builtin_amdgcn_readlane(idxreg, min(i + 4, dm1));
            int s2b = __builtin_amdgcn_readlane(idxreg, min(i + 5, dm1));
            uint32_t uA2 = xrw[(size_t)s2a * 64 + lane];
            uint32_t uB2 = xrw[(size_t)s2b * 64 + lane];

            float a0 = bf_lo(uA0), a1 = bf_hi(uA0);
            float b0 = bf_lo(uB0), b1 = bf_hi(uB0);
            float tA = sum16(lrelu(qv[0] + a0) * av[0] + lrelu(qv[1] + a1) * av[1]);
            float tB = sum16(lrelu(qv[0] + b0) * av[0] + lrelu(qv[1] + b1) * av[1]);
            float wA = __expf(tA), wB = __expf(tB);
            lsum += wA + wB;
            acc0 += wA * a0 + wB * b0;
            acc1 += wA * a1 + wB * b1;

            uA0 = uA1; uB0 = uB1;
            uA1 = uA2; uB1 = uB2;
            i += 2;
        }
        if (i < deg) {   // odd tail: uA0 holds edge i (pipeline invariant)
            float a0 = bf_lo(uA0), a1 = bf_hi(uA0);
            float tA = sum16(lrelu(qv[0] + a0) * av[0] + lrelu(qv[1] + a1) * av[1]);
            float wA = __expf(tA);
            lsum += wA;
            acc0 += wA * a0;
            acc1 += wA * a1;
        }
    }

    float inv = 1.f / lsum;
    f32x2 ov;
    ov[0] = acc0 * inv + bv[0];
    ov[1] = acc1 * inv + bv[1];
    *(f32x2*)(out + (size_t)n * IN_CH + 2 * lane) = ov;
}

extern "C" void kernel_launch(void* const* d_in, const int* in_sizes, int n_in,
                              void* d_out, int out_size, void* d_ws, size_t ws_size,
                              hipStream_t stream) {
    const float* x    = (const float*)d_in[0];
    const int*   ei   = (const int*)d_in[1];
    const float* Wl   = (const float*)d_in[2];
    const float* bl   = (const float*)d_in[3];
    const float* Wr   = (const float*)d_in[4];
    const float* br   = (const float*)d_in[5];
    const float* att  = (const float*)d_in[6];
    const float* bias = (const float*)d_in[7];
    float* out = (float*)d_out;

    // workspace layout (bytes):
    //   xr    : [0, 12.8M)                bf16 [N, 128]
    //   wswz  : [12.8M, 12.8M+65536)      bf16 [4096*8]  (swizzled Wl|Wr)
    //   slabs : [12865536, +N*128)        per-node [u32 cnt][62 x u16 nbr]
    // xl lives in d_out as f32 (each node's wave reads its own row first).
    char* ws = (char*)d_ws;
    __hip_bfloat16* xr   = (__hip_bfloat16*)(ws);
    __hip_bfloat16* wswz = (__hip_bfloat16*)(ws + 12800000);

    const size_t SLAB_BASE = 12865536;
    char* cbase; char* ebase;
    int cstride, estride, cap;
    size_t zbytes;
    if (ws_size >= SLAB_BASE + (size_t)N_NODES * 128) {
        // slab mode: counter + neighbor list share one 128B line per node
        cbase = ws + SLAB_BASE;  cstride = 128;
        ebase = cbase + 4;       estride = 128;
        cap = 62;
        zbytes = (size_t)N_NODES * 128;
    } else {
        // legacy split arrays (small-ws fallback)
        cbase = ws + SLAB_BASE;  cstride = 4;
        ebase = ws + SLAB_BASE + 200000;
        long long avail = (ws_size > SLAB_BASE + 200000)
                        ? (long long)(ws_size - SLAB_BASE - 200000) : 0;
        cap = (int)(avail / ((long long)N_NODES * 2));
        if (cap > 64) cap = 64;
        if (cap < 1)  cap = 1;
        estride = 2 * cap;
        zbytes = 200000;
    }

    prep_kernel<<<64, 256, 0, stream>>>(Wl, Wr, wswz, (i32x4*)cbase, (int)(zbytes / 16));
    mid_kernel<<<PROJ_BLOCKS + FILL_BLOCKS, 256, 0, stream>>>(
        x, wswz, bl, br, out, xr, ei, cap, cbase, cstride, ebase, estride);
    agg_kernel<<<N_NODES / 4, 256, 0, stream>>>(
        xr, cbase, cstride, ebase, estride, cap, att, bias, out);
}